// Round 1
// baseline (1629.366 us; speedup 1.0000x reference)
//
#include <hip/hip_runtime.h>

#define HID 128
#define OUTD 64
#define N_SOTU 500000
#define N_TAXON 200000
#define E_TT 200000
#define E_TS 1000000
#define E_LBL 500000
#define HALF_S 250000
#define SCAN_TILE 2048   // elements per scan block (256 thr x 8)

typedef short s16x8 __attribute__((ext_vector_type(8)));   // 8 bf16 (4 VGPRs) MFMA frag
typedef float f32x4 __attribute__((ext_vector_type(4)));

__device__ __forceinline__ unsigned short f2bf(float f) {  // f32 -> bf16 bits, RNE
    unsigned u = __builtin_bit_cast(unsigned, f);
    u += 0x7FFFu + ((u >> 16) & 1u);
    return (unsigned short)(u >> 16);
}
__device__ __forceinline__ float bf2f(unsigned short h) {
    unsigned u = ((unsigned)h) << 16;
    return __builtin_bit_cast(float, u);
}

// =================== CSR build: hist -> scan (3 kernels) -> fill ===================
__global__ void hist_kernel(const int* __restrict__ dst, int n, int* __restrict__ rp) {
    int e = blockIdx.x * 256 + threadIdx.x;
    if (e < n) atomicAdd(&rp[dst[e]], 1);
}

// in-place inclusive scan within SCAN_TILE blocks; bsums[b] = block total
__global__ __launch_bounds__(256) void scan1_kernel(int* __restrict__ a, int n, int* __restrict__ bsums) {
    __shared__ int tsum[256];
    const int t = threadIdx.x;
    const int base = blockIdx.x * SCAN_TILE + t * 8;
    int v[8]; int s = 0;
#pragma unroll
    for (int i = 0; i < 8; i++) {
        int x = (base + i < n) ? a[base + i] : 0;
        s += x; v[i] = s;                       // thread-local inclusive
    }
    tsum[t] = s;
    __syncthreads();
    for (int off = 1; off < 256; off <<= 1) {   // Hillis-Steele inclusive over 256
        int x = (t >= off) ? tsum[t - off] : 0;
        __syncthreads();
        tsum[t] += x;
        __syncthreads();
    }
    const int prev = (t > 0) ? tsum[t - 1] : 0;
#pragma unroll
    for (int i = 0; i < 8; i++)
        if (base + i < n) a[base + i] = v[i] + prev;
    if (t == 255) bsums[blockIdx.x] = tsum[255];
}

// single-block inclusive scan of bsums (nb <= 256)
__global__ __launch_bounds__(256) void scan2_kernel(int* __restrict__ bsums, int nb) {
    __shared__ int tsum[256];
    const int t = threadIdx.x;
    tsum[t] = (t < nb) ? bsums[t] : 0;
    __syncthreads();
    for (int off = 1; off < 256; off <<= 1) {
        int x = (t >= off) ? tsum[t - off] : 0;
        __syncthreads();
        tsum[t] += x;
        __syncthreads();
    }
    if (t < nb) bsums[t] = tsum[t];
}

__global__ __launch_bounds__(256) void scan3_kernel(int* __restrict__ a, int n, const int* __restrict__ bsums) {
    const int b = blockIdx.x;
    if (b == 0) return;
    const int add = bsums[b - 1];
    const int base = b * SCAN_TILE + threadIdx.x * 8;
#pragma unroll
    for (int i = 0; i < 8; i++)
        if (base + i < n) a[base + i] += add;
}

// fill buckets back-to-front; afterwards rp[d] = bucket start
__global__ void fill_kernel(const int* __restrict__ src, const int* __restrict__ dst, int n,
                            int* __restrict__ rp, int* __restrict__ sl) {
    int e = blockIdx.x * 256 + threadIdx.x;
    if (e < n) {
        int pos = atomicSub(&rp[dst[e]], 1) - 1;
        sl[pos] = src[e];
    }
}

// =================== gather mean: agg_bf16[d-lo] = mean_{j in bucket d} x[sl[j]] ==============
// 16 lanes per dst row, 8 feats/lane. Source f32 (xf, optional xids) or bf16 (xb).
__global__ __launch_bounds__(256) void gather_kernel(
    const float* __restrict__ xf, const unsigned short* __restrict__ xb,
    const int* __restrict__ xids,
    const int* __restrict__ rp, const int* __restrict__ sl,
    int n_dst_total, int n_edges, int lo, int rows,
    unsigned short* __restrict__ agg)
{
    const int g = blockIdx.x * 16 + (threadIdx.x >> 4);
    if (g >= rows) return;
    const int d = lo + g;
    const int l = threadIdx.x & 15;
    const int start = rp[d];
    const int end = (d + 1 < n_dst_total) ? rp[d + 1] : n_edges;
    float acc[8] = {0.f, 0.f, 0.f, 0.f, 0.f, 0.f, 0.f, 0.f};
    for (int j = start; j < end; ++j) {
        int s = sl[j];
        if (xids) s = xids[s];
        if (xf) {
            const float* p = xf + (size_t)s * HID + l * 8;
            float4 v0 = *(const float4*)p;
            float4 v1 = *(const float4*)(p + 4);
            acc[0] += v0.x; acc[1] += v0.y; acc[2] += v0.z; acc[3] += v0.w;
            acc[4] += v1.x; acc[5] += v1.y; acc[6] += v1.z; acc[7] += v1.w;
        } else {
            s16x8 b = *(const s16x8*)(xb + (size_t)s * HID + l * 8);
#pragma unroll
            for (int i = 0; i < 8; i++) acc[i] += bf2f((unsigned short)b[i]);
        }
    }
    const float inv = (end > start) ? 1.0f / (float)(end - start) : 0.0f;
    s16x8 o;
#pragma unroll
    for (int i = 0; i < 8; i++) o[i] = (short)f2bf(acc[i] * inv);
    *(s16x8*)(agg + (size_t)g * HID + l * 8) = o;
}

// =================== fused SAGE: out = relu( agg@wl + x@wr + bl ) ===================
// MFMA 16x16x32 bf16, K=256 (concat [agg | x]), N=128. Weights bf16 in LDS, transposed +
// XOR-granule-swizzled.
__device__ __forceinline__ int wt_idx(int n, int k) {
    return n * 256 + ((((k >> 3) ^ n) & 31) << 3) + (k & 7);
}

__global__ __launch_bounds__(256) void sage_kernel(
    int n_rows, int row0,
    const unsigned short* __restrict__ agg,   // bf16 mean, local rows [0, n_rows)
    const float* __restrict__ xf, const unsigned short* __restrict__ xb,  // one non-null
    const int* __restrict__ xids,    // pre-offset by row0; if null, xrow = row0 + local
    const float* __restrict__ wl, const float* __restrict__ wr,
    const float* __restrict__ bl,
    unsigned short* __restrict__ out)  // pre-offset by row0*HID
{
    __shared__ __align__(16) unsigned short WT[128 * 256];  // 64 KB: WT[n][k], k<128 wl, k>=128 wr
    for (int idx = threadIdx.x; idx < 128 * 128; idx += 256) {
        int n = idx & 127, k = idx >> 7;
        WT[wt_idx(n, k)]       = f2bf(wl[idx]);   // wl[k][n]
        WT[wt_idx(n, k + 128)] = f2bf(wr[idx]);   // wr[k][n]
    }
    __syncthreads();
    const int lane = threadIdx.x & 63, wid = threadIdx.x >> 6;
    const int l16 = lane & 15, q = lane >> 4;
    const int n_tiles = n_rows >> 4;
    const int stride = gridDim.x * 4;
    for (int tile = blockIdx.x * 4 + wid; tile < n_tiles; tile += stride) {
        const int base = tile << 4;
        const int lrow = base + l16;     // A-operand row (local) this lane feeds
        const size_t xrow = xids ? (size_t)xids[lrow] : (size_t)(row0 + lrow);
        f32x4 acc[8] = {};
        // K = 0..127 : aggregation (bf16 direct)
#pragma unroll
        for (int ks = 0; ks < 4; ks++) {
            s16x8 a = *(const s16x8*)(agg + (size_t)lrow * HID + ks * 32 + q * 8);
            const int kb = ks * 32 + q * 8;
#pragma unroll
            for (int nt = 0; nt < 8; nt++) {
                s16x8 b = *(const s16x8*)&WT[wt_idx(nt * 16 + l16, kb)];
                acc[nt] = __builtin_amdgcn_mfma_f32_16x16x32_bf16(a, b, acc[nt], 0, 0, 0);
            }
        }
        // K = 128..255 : x_dst
#pragma unroll
        for (int ks = 0; ks < 4; ks++) {
            s16x8 a;
            if (xf) {
                const float* xp = xf + xrow * HID + ks * 32 + q * 8;
                float4 v0 = *(const float4*)xp;
                float4 v1 = *(const float4*)(xp + 4);
                a[0] = (short)f2bf(v0.x); a[1] = (short)f2bf(v0.y);
                a[2] = (short)f2bf(v0.z); a[3] = (short)f2bf(v0.w);
                a[4] = (short)f2bf(v1.x); a[5] = (short)f2bf(v1.y);
                a[6] = (short)f2bf(v1.z); a[7] = (short)f2bf(v1.w);
            } else {
                a = *(const s16x8*)(xb + xrow * HID + ks * 32 + q * 8);
            }
            const int kb = 128 + ks * 32 + q * 8;
#pragma unroll
            for (int nt = 0; nt < 8; nt++) {
                s16x8 b = *(const s16x8*)&WT[wt_idx(nt * 16 + l16, kb)];
                acc[nt] = __builtin_amdgcn_mfma_f32_16x16x32_bf16(a, b, acc[nt], 0, 0, 0);
            }
        }
        // epilogue. D layout (m89-verified): col = lane&15, row = (lane>>4)*4 + i
#pragma unroll
        for (int nt = 0; nt < 8; nt++) {
            const int n = nt * 16 + l16;
            const float bv = bl[n];
#pragma unroll
            for (int i = 0; i < 4; i++) {
                float v = acc[nt][i] + bv;
                out[(size_t)(base + q * 4 + i) * HID + n] = f2bf(fmaxf(v, 0.0f));
            }
        }
    }
}

// =================== linear head: z = x @ w + b  ([N,128]@[128,64]) ===================
__global__ __launch_bounds__(256) void proj_kernel(
    int n_nodes, const unsigned short* __restrict__ x,
    const float* __restrict__ w, const float* __restrict__ bias, unsigned short* __restrict__ z)
{
    const int lane = threadIdx.x & 63, wid = threadIdx.x >> 6;
    const int l16 = lane & 15, q = lane >> 4;
    s16x8 bfr[4][4];
#pragma unroll
    for (int ks = 0; ks < 4; ks++)
#pragma unroll
        for (int nt = 0; nt < 4; nt++)
#pragma unroll
            for (int i = 0; i < 8; i++)
                bfr[ks][nt][i] = (short)f2bf(w[(ks * 32 + q * 8 + i) * OUTD + nt * 16 + l16]);
    const int n_tiles = n_nodes >> 4;
    const int stride = gridDim.x * 4;
    for (int tile = blockIdx.x * 4 + wid; tile < n_tiles; tile += stride) {
        const int base = tile << 4;
        const size_t mrow = (size_t)(base + l16);
        f32x4 acc[4] = {};
#pragma unroll
        for (int ks = 0; ks < 4; ks++) {
            s16x8 a = *(const s16x8*)(x + mrow * HID + ks * 32 + q * 8);
#pragma unroll
            for (int nt = 0; nt < 4; nt++)
                acc[nt] = __builtin_amdgcn_mfma_f32_16x16x32_bf16(a, bfr[ks][nt], acc[nt], 0, 0, 0);
        }
#pragma unroll
        for (int nt = 0; nt < 4; nt++) {
            const int n = nt * 16 + l16;
            const float bv = bias[n];
#pragma unroll
            for (int i = 0; i < 4; i++)
                z[(size_t)(base + q * 4 + i) * OUTD + n] = f2bf(acc[nt][i] + bv);
        }
    }
}

// =================== edge decoder ===================
__global__ __launch_bounds__(256) void dec_kernel(
    const int* __restrict__ erow, const int* __restrict__ ecol,
    const unsigned short* __restrict__ zs, const unsigned short* __restrict__ zt,
    const float* __restrict__ w1, const float* __restrict__ b1,
    const float* __restrict__ w2, const float* __restrict__ b2,
    float* __restrict__ out)
{
    const int lane = threadIdx.x & 63, wid = threadIdx.x >> 6;
    const int l16 = lane & 15, q = lane >> 4;
    s16x8 bfr[4][4];  // d1_w [128][64] as B-fragments
#pragma unroll
    for (int ks = 0; ks < 4; ks++)
#pragma unroll
        for (int nt = 0; nt < 4; nt++)
#pragma unroll
            for (int i = 0; i < 8; i++)
                bfr[ks][nt][i] = (short)f2bf(w1[(ks * 32 + q * 8 + i) * OUTD + nt * 16 + l16]);
    float b1v[4], w2v[4];
#pragma unroll
    for (int nt = 0; nt < 4; nt++) {
        b1v[nt] = b1[nt * 16 + l16];
        w2v[nt] = w2[nt * 16 + l16];
    }
    const float b2v = b2[0];
    const int n_tiles = E_LBL >> 4;
    for (int tile = blockIdx.x * 4 + wid; tile < n_tiles; tile += gridDim.x * 4) {
        const int em = tile * 16 + l16;
        const size_t r = (size_t)erow[em], c = (size_t)ecol[em];
        f32x4 acc[4] = {};
        s16x8 a0 = *(const s16x8*)(zs + r * OUTD + q * 8);
        s16x8 a1 = *(const s16x8*)(zs + r * OUTD + 32 + q * 8);
        s16x8 a2 = *(const s16x8*)(zt + c * OUTD + q * 8);
        s16x8 a3 = *(const s16x8*)(zt + c * OUTD + 32 + q * 8);
#pragma unroll
        for (int nt = 0; nt < 4; nt++) {
            acc[nt] = __builtin_amdgcn_mfma_f32_16x16x32_bf16(a0, bfr[0][nt], acc[nt], 0, 0, 0);
            acc[nt] = __builtin_amdgcn_mfma_f32_16x16x32_bf16(a1, bfr[1][nt], acc[nt], 0, 0, 0);
            acc[nt] = __builtin_amdgcn_mfma_f32_16x16x32_bf16(a2, bfr[2][nt], acc[nt], 0, 0, 0);
            acc[nt] = __builtin_amdgcn_mfma_f32_16x16x32_bf16(a3, bfr[3][nt], acc[nt], 0, 0, 0);
        }
        float s[4] = {0.0f, 0.0f, 0.0f, 0.0f};
#pragma unroll
        for (int nt = 0; nt < 4; nt++)
#pragma unroll
            for (int i = 0; i < 4; i++)
                s[i] += fmaxf(acc[nt][i] + b1v[nt], 0.0f) * w2v[nt];
#pragma unroll
        for (int off = 8; off >= 1; off >>= 1)
#pragma unroll
            for (int i = 0; i < 4; i++)
                s[i] += __shfl_down(s[i], off, 16);
        if (l16 == 0) {
#pragma unroll
            for (int i = 0; i < 4; i++)
                out[tile * 16 + q * 4 + i] = s[i] + b2v;
        }
    }
}

// =================== host side ===================
static void build_csr(const int* src, const int* dst, int n_edges, int n_dst,
                      int* rp, int* sl, int* bsums, hipStream_t stream) {
    hipMemsetAsync(rp, 0, (size_t)n_dst * 4, stream);
    hist_kernel<<<(n_edges + 255) / 256, 256, 0, stream>>>(dst, n_edges, rp);
    const int nb = (n_dst + SCAN_TILE - 1) / SCAN_TILE;   // <= 245, fits scan2's 256
    scan1_kernel<<<nb, 256, 0, stream>>>(rp, n_dst, bsums);
    scan2_kernel<<<1, 256, 0, stream>>>(bsums, nb);
    scan3_kernel<<<nb, 256, 0, stream>>>(rp, n_dst, bsums);
    fill_kernel<<<(n_edges + 255) / 256, 256, 0, stream>>>(src, dst, n_edges, rp, sl);
}

extern "C" void kernel_launch(void* const* d_in, const int* in_sizes, int n_in,
                              void* d_out, int out_size, void* d_ws, size_t ws_size,
                              hipStream_t stream) {
    (void)in_sizes; (void)n_in; (void)out_size; (void)ws_size;
    const int* sotu_ids  = (const int*)d_in[0];
    const int* taxon_ids = (const int*)d_in[1];
    const int* ett_src   = (const int*)d_in[2];
    const int* ett_dst   = (const int*)d_in[3];
    const int* ets_src   = (const int*)d_in[4];
    const int* ets_dst   = (const int*)d_in[5];
    const int* elbl_row  = (const int*)d_in[6];
    const int* elbl_col  = (const int*)d_in[7];
    const float* sotu_emb  = (const float*)d_in[8];
    const float* taxon_emb = (const float*)d_in[9];
    const float* s1_wl = (const float*)d_in[10]; const float* s1_bl = (const float*)d_in[11]; const float* s1_wr = (const float*)d_in[12];
    const float* s2_wl = (const float*)d_in[13]; const float* s2_bl = (const float*)d_in[14]; const float* s2_wr = (const float*)d_in[15];
    const float* s3_wl = (const float*)d_in[16]; const float* s3_bl = (const float*)d_in[17]; const float* s3_wr = (const float*)d_in[18];
    const float* sl_w  = (const float*)d_in[19]; const float* sl_b  = (const float*)d_in[20];
    const float* t1_wl = (const float*)d_in[21]; const float* t1_bl = (const float*)d_in[22]; const float* t1_wr = (const float*)d_in[23];
    const float* t2_wl = (const float*)d_in[24]; const float* t2_bl = (const float*)d_in[25]; const float* t2_wr = (const float*)d_in[26];
    const float* tl_w  = (const float*)d_in[27]; const float* tl_b  = (const float*)d_in[28];
    const float* d1_w  = (const float*)d_in[29]; const float* d1_b  = (const float*)d_in[30];
    const float* d2_w  = (const float*)d_in[31]; const float* d2_b  = (const float*)d_in[32];
    float* out = (float*)d_out;

    // workspace (~328 MB)
    char* ws = (char*)d_ws;
    size_t off = 0;
    auto alloc = [&](size_t bytes) { void* p = ws + off; off = (off + bytes + 255) & ~(size_t)255; return p; };
    unsigned short* agg     = (unsigned short*)alloc((size_t)HALF_S * HID * 2);   // 64 MB (bf16 mean)
    unsigned short* taxon_x = (unsigned short*)alloc((size_t)N_TAXON * HID * 2);  // 51.2 MB
    unsigned short* tx1     = (unsigned short*)alloc((size_t)N_TAXON * HID * 2);  // 51.2 MB
    unsigned short* sotu_x  = (unsigned short*)alloc((size_t)N_SOTU * HID * 2);   // 128 MB
    unsigned short* z_taxon = (unsigned short*)alloc((size_t)N_TAXON * OUTD * 2); // 25.6 MB
    int* rp_ts = (int*)alloc((size_t)N_SOTU * 4);    // 2 MB
    int* sl_ts = (int*)alloc((size_t)E_TS * 4);      // 4 MB
    int* rp_tt = (int*)alloc((size_t)N_TAXON * 4);   // 0.8 MB
    int* sl_tt = (int*)alloc((size_t)E_TT * 4);      // 0.8 MB
    int* bsums = (int*)alloc(256 * 4);
    unsigned short* z_sotu = agg;   // 64 MB alias; agg dead after last s3 sage

    // CSR builds (tt used by A1 and T2; ts by A2 and A3)
    build_csr(ett_src, ett_dst, E_TT, N_TAXON, rp_tt, sl_tt, bsums, stream);
    build_csr(ets_src, ets_dst, E_TS, N_SOTU, rp_ts, sl_ts, bsums, stream);

    // A1 = mean_{ett} x_taxon (shared by s1/t1)
    gather_kernel<<<(N_TAXON + 15) / 16, 256, 0, stream>>>(
        taxon_emb, nullptr, taxon_ids, rp_tt, sl_tt, N_TAXON, E_TT, 0, N_TAXON, agg);
    sage_kernel<<<512, 256, 0, stream>>>(N_TAXON, 0, agg, taxon_emb, nullptr, taxon_ids,
                                         s1_wl, s1_wr, s1_bl, taxon_x);
    sage_kernel<<<512, 256, 0, stream>>>(N_TAXON, 0, agg, taxon_emb, nullptr, taxon_ids,
                                         t1_wl, t1_wr, t1_bl, tx1);

    // taxon tail: T2 = mean_{ett} tx1 ; t2 (in-place) ; tl head
    gather_kernel<<<(N_TAXON + 15) / 16, 256, 0, stream>>>(
        nullptr, tx1, nullptr, rp_tt, sl_tt, N_TAXON, E_TT, 0, N_TAXON, agg);
    sage_kernel<<<512, 256, 0, stream>>>(N_TAXON, 0, agg, nullptr, tx1, nullptr,
                                         t2_wl, t2_wr, t2_bl, tx1);
    proj_kernel<<<1024, 256, 0, stream>>>(N_TAXON, tx1, tl_w, tl_b, z_taxon);

    // s2: A2 = mean_{ets} x_taxon -> sotu (two dst-halves)
    for (int h = 0; h < 2; ++h) {
        int lo = h * HALF_S;
        gather_kernel<<<(HALF_S + 15) / 16, 256, 0, stream>>>(
            taxon_emb, nullptr, taxon_ids, rp_ts, sl_ts, N_SOTU, E_TS, lo, HALF_S, agg);
        sage_kernel<<<512, 256, 0, stream>>>(HALF_S, lo, agg, sotu_emb, nullptr, sotu_ids + lo,
                                             s2_wl, s2_wr, s2_bl, sotu_x + (size_t)lo * HID);
    }
    // s3: A3 = mean_{ets} taxon_x -> sotu (two dst-halves, in-place on sotu_x)
    for (int h = 0; h < 2; ++h) {
        int lo = h * HALF_S;
        gather_kernel<<<(HALF_S + 15) / 16, 256, 0, stream>>>(
            nullptr, taxon_x, nullptr, rp_ts, sl_ts, N_SOTU, E_TS, lo, HALF_S, agg);
        sage_kernel<<<512, 256, 0, stream>>>(HALF_S, lo, agg, nullptr, sotu_x, nullptr,
                                             s3_wl, s3_wr, s3_bl, sotu_x + (size_t)lo * HID);
    }
    // sl head (agg dead -> z_sotu lives there)
    proj_kernel<<<1024, 256, 0, stream>>>(N_SOTU, sotu_x, sl_w, sl_b, z_sotu);

    // edge decoder
    dec_kernel<<<1024, 256, 0, stream>>>(elbl_row, elbl_col, z_sotu, z_taxon,
                                         d1_w, d1_b, d2_w, d2_b, out);
}

// Round 2
// 1495.237 us; speedup vs baseline: 1.0897x; 1.0897x over previous
//
#include <hip/hip_runtime.h>

#define HID 128
#define OUTD 64
#define N_SOTU 500000
#define N_TAXON 200000
#define E_TT 200000
#define E_TS 1000000
#define E_LBL 500000
#define SCAN_TILE 2048   // elements per scan block (256 thr x 8)

typedef short s16x8 __attribute__((ext_vector_type(8)));   // 8 bf16 (4 VGPRs) MFMA frag
typedef float f32x4 __attribute__((ext_vector_type(4)));

__device__ __forceinline__ unsigned short f2bf(float f) {  // f32 -> bf16 bits, RNE
    unsigned u = __builtin_bit_cast(unsigned, f);
    u += 0x7FFFu + ((u >> 16) & 1u);
    return (unsigned short)(u >> 16);
}
__device__ __forceinline__ float bf2f(unsigned short h) {
    unsigned u = ((unsigned)h) << 16;
    return __builtin_bit_cast(float, u);
}

// =================== CSR build: hist -> scan (3 kernels) -> fill ===================
__global__ void hist_kernel(const int* __restrict__ dst, int n, int* __restrict__ rp) {
    int e = blockIdx.x * 256 + threadIdx.x;
    if (e < n) atomicAdd(&rp[dst[e]], 1);
}

__global__ __launch_bounds__(256) void scan1_kernel(int* __restrict__ a, int n, int* __restrict__ bsums) {
    __shared__ int tsum[256];
    const int t = threadIdx.x;
    const int base = blockIdx.x * SCAN_TILE + t * 8;
    int v[8]; int s = 0;
#pragma unroll
    for (int i = 0; i < 8; i++) {
        int x = (base + i < n) ? a[base + i] : 0;
        s += x; v[i] = s;
    }
    tsum[t] = s;
    __syncthreads();
    for (int off = 1; off < 256; off <<= 1) {
        int x = (t >= off) ? tsum[t - off] : 0;
        __syncthreads();
        tsum[t] += x;
        __syncthreads();
    }
    const int prev = (t > 0) ? tsum[t - 1] : 0;
#pragma unroll
    for (int i = 0; i < 8; i++)
        if (base + i < n) a[base + i] = v[i] + prev;
    if (t == 255) bsums[blockIdx.x] = tsum[255];
}

__global__ __launch_bounds__(256) void scan2_kernel(int* __restrict__ bsums, int nb) {
    __shared__ int tsum[256];
    const int t = threadIdx.x;
    tsum[t] = (t < nb) ? bsums[t] : 0;
    __syncthreads();
    for (int off = 1; off < 256; off <<= 1) {
        int x = (t >= off) ? tsum[t - off] : 0;
        __syncthreads();
        tsum[t] += x;
        __syncthreads();
    }
    if (t < nb) bsums[t] = tsum[t];
}

__global__ __launch_bounds__(256) void scan3_kernel(int* __restrict__ a, int n, const int* __restrict__ bsums) {
    const int b = blockIdx.x;
    if (b == 0) return;
    const int add = bsums[b - 1];
    const int base = b * SCAN_TILE + threadIdx.x * 8;
#pragma unroll
    for (int i = 0; i < 8; i++)
        if (base + i < n) a[base + i] += add;
}

__global__ void fill_kernel(const int* __restrict__ src, const int* __restrict__ dst, int n,
                            int* __restrict__ rp, int* __restrict__ sl) {
    int e = blockIdx.x * 256 + threadIdx.x;
    if (e < n) {
        int pos = atomicSub(&rp[dst[e]], 1) - 1;
        sl[pos] = src[e];
    }
}

// =================== embedding f32 -> bf16 (with id indirection baked in) ===================
__global__ __launch_bounds__(256) void cvt_kernel(
    int n_rows, const float* __restrict__ xf, const int* __restrict__ ids,
    unsigned short* __restrict__ o)
{
    int idx = blockIdx.x * 256 + threadIdx.x;     // one thread = 8 feats
    if (idx >= n_rows * 16) return;
    int r = idx >> 4, l = idx & 15;
    int s = ids ? ids[r] : r;
    const float* p = xf + (size_t)s * HID + l * 8;
    float4 v0 = *(const float4*)p;
    float4 v1 = *(const float4*)(p + 4);
    s16x8 ov;
    ov[0] = (short)f2bf(v0.x); ov[1] = (short)f2bf(v0.y);
    ov[2] = (short)f2bf(v0.z); ov[3] = (short)f2bf(v0.w);
    ov[4] = (short)f2bf(v1.x); ov[5] = (short)f2bf(v1.y);
    ov[6] = (short)f2bf(v1.z); ov[7] = (short)f2bf(v1.w);
    *(s16x8*)(o + (size_t)r * HID + l * 8) = ov;
}

// =================== fused gather + SAGE ===================
// out = relu( mean_{nb}(gsrc) @ wl + x @ wr + bl ).  Per-wave: gather 16-row tile's means
// into swizzled LDS (4 KB/wave), then MFMA 16x16x32 bf16 with K=256 = [agg | x].
__device__ __forceinline__ int wt_idx(int n, int k) {
    return n * 256 + ((((k >> 3) ^ n) & 31) << 3) + (k & 7);
}

__global__ __launch_bounds__(256) void fsage_kernel(
    int n_rows, int row0,
    const unsigned short* __restrict__ gsrc,   // gather source rows, bf16 [*, HID]
    const int* __restrict__ rp, const int* __restrict__ sl,
    int n_dst_total, int n_edges,
    const float* __restrict__ xf, const unsigned short* __restrict__ xb,  // one non-null
    const int* __restrict__ xids,    // if null, xrow = row0 + local
    const float* __restrict__ wl, const float* __restrict__ wr,
    const float* __restrict__ bl,
    unsigned short* __restrict__ out)  // pre-offset by row0*HID
{
    __shared__ __align__(16) unsigned short WT[128 * 256];       // 64 KB weights
    __shared__ __align__(16) unsigned short AGG[4][16 * 128];    // 16 KB per-wave staging
    for (int idx = threadIdx.x; idx < 128 * 128; idx += 256) {
        int n = idx & 127, k = idx >> 7;
        WT[wt_idx(n, k)]       = f2bf(wl[idx]);   // wl[k][n]
        WT[wt_idx(n, k + 128)] = f2bf(wr[idx]);   // wr[k][n]
    }
    __syncthreads();
    const int lane = threadIdx.x & 63, wid = threadIdx.x >> 6;
    const int l16 = lane & 15, q = lane >> 4;
    const int n_tiles = n_rows >> 4;
    const int stride = gridDim.x * 4;
    for (int tile = blockIdx.x * 4 + wid; tile < n_tiles; tile += stride) {
        const int base = tile << 4;
        // ---- gather phase: 4 rows at a time, 16 lanes/row (lane q = row sub-idx) ----
#pragma unroll
        for (int it = 0; it < 4; ++it) {
            const int lr = it * 4 + q;             // local row in tile, 0..15
            const int d = row0 + base + lr;        // global dst id
            const int start = rp[d];
            const int end = (d + 1 < n_dst_total) ? rp[d + 1] : n_edges;
            float acc[8] = {0.f, 0.f, 0.f, 0.f, 0.f, 0.f, 0.f, 0.f};
            for (int j = start; j < end; ++j) {
                const int s = sl[j];
                s16x8 b = *(const s16x8*)(gsrc + (size_t)s * HID + l16 * 8);
#pragma unroll
                for (int i = 0; i < 8; i++) acc[i] += bf2f((unsigned short)b[i]);
            }
            const float inv = (end > start) ? 1.0f / (float)(end - start) : 0.0f;
            s16x8 o;
#pragma unroll
            for (int i = 0; i < 8; i++) o[i] = (short)f2bf(acc[i] * inv);
            // XOR-swizzled store (16B granule): col_us = l16*8 ^ ((lr&7)<<3)
            *(s16x8*)&AGG[wid][lr * 128 + ((l16 * 8) ^ ((lr & 7) << 3))] = o;
        }
        asm volatile("s_waitcnt lgkmcnt(0)" ::: "memory");   // wave-local: writes visible to all lanes
        // ---- MFMA phase ----
        const int lrow = base + l16;
        const size_t xrow = xids ? (size_t)xids[lrow] : (size_t)(row0 + lrow);
        f32x4 acc[8] = {};
        // K = 0..127 : aggregation from swizzled LDS
#pragma unroll
        for (int ks = 0; ks < 4; ks++) {
            const int cu = ks * 32 + q * 8;
            s16x8 a = *(const s16x8*)&AGG[wid][l16 * 128 + (cu ^ ((l16 & 7) << 3))];
#pragma unroll
            for (int nt = 0; nt < 8; nt++) {
                s16x8 b = *(const s16x8*)&WT[wt_idx(nt * 16 + l16, cu)];
                acc[nt] = __builtin_amdgcn_mfma_f32_16x16x32_bf16(a, b, acc[nt], 0, 0, 0);
            }
        }
        // K = 128..255 : x_dst
#pragma unroll
        for (int ks = 0; ks < 4; ks++) {
            s16x8 a;
            if (xf) {
                const float* xp = xf + xrow * HID + ks * 32 + q * 8;
                float4 v0 = *(const float4*)xp;
                float4 v1 = *(const float4*)(xp + 4);
                a[0] = (short)f2bf(v0.x); a[1] = (short)f2bf(v0.y);
                a[2] = (short)f2bf(v0.z); a[3] = (short)f2bf(v0.w);
                a[4] = (short)f2bf(v1.x); a[5] = (short)f2bf(v1.y);
                a[6] = (short)f2bf(v1.z); a[7] = (short)f2bf(v1.w);
            } else {
                a = *(const s16x8*)(xb + xrow * HID + ks * 32 + q * 8);
            }
            const int kb = 128 + ks * 32 + q * 8;
#pragma unroll
            for (int nt = 0; nt < 8; nt++) {
                s16x8 b = *(const s16x8*)&WT[wt_idx(nt * 16 + l16, kb)];
                acc[nt] = __builtin_amdgcn_mfma_f32_16x16x32_bf16(a, b, acc[nt], 0, 0, 0);
            }
        }
        // epilogue. D layout (m89-verified): col = lane&15, row = (lane>>4)*4 + i
#pragma unroll
        for (int nt = 0; nt < 8; nt++) {
            const int n = nt * 16 + l16;
            const float bv = bl[n];
#pragma unroll
            for (int i = 0; i < 4; i++) {
                float v = acc[nt][i] + bv;
                out[(size_t)(base + q * 4 + i) * HID + n] = f2bf(fmaxf(v, 0.0f));
            }
        }
    }
}

// =================== linear head: z = x @ w + b  ([N,128]@[128,64]) ===================
__global__ __launch_bounds__(256) void proj_kernel(
    int n_nodes, const unsigned short* __restrict__ x,
    const float* __restrict__ w, const float* __restrict__ bias, unsigned short* __restrict__ z)
{
    const int lane = threadIdx.x & 63, wid = threadIdx.x >> 6;
    const int l16 = lane & 15, q = lane >> 4;
    s16x8 bfr[4][4];
#pragma unroll
    for (int ks = 0; ks < 4; ks++)
#pragma unroll
        for (int nt = 0; nt < 4; nt++)
#pragma unroll
            for (int i = 0; i < 8; i++)
                bfr[ks][nt][i] = (short)f2bf(w[(ks * 32 + q * 8 + i) * OUTD + nt * 16 + l16]);
    const int n_tiles = n_nodes >> 4;
    const int stride = gridDim.x * 4;
    for (int tile = blockIdx.x * 4 + wid; tile < n_tiles; tile += stride) {
        const int base = tile << 4;
        const size_t mrow = (size_t)(base + l16);
        f32x4 acc[4] = {};
#pragma unroll
        for (int ks = 0; ks < 4; ks++) {
            s16x8 a = *(const s16x8*)(x + mrow * HID + ks * 32 + q * 8);
#pragma unroll
            for (int nt = 0; nt < 4; nt++)
                acc[nt] = __builtin_amdgcn_mfma_f32_16x16x32_bf16(a, bfr[ks][nt], acc[nt], 0, 0, 0);
        }
#pragma unroll
        for (int nt = 0; nt < 4; nt++) {
            const int n = nt * 16 + l16;
            const float bv = bias[n];
#pragma unroll
            for (int i = 0; i < 4; i++)
                z[(size_t)(base + q * 4 + i) * OUTD + n] = f2bf(acc[nt][i] + bv);
        }
    }
}

// =================== edge decoder ===================
__global__ __launch_bounds__(256) void dec_kernel(
    const int* __restrict__ erow, const int* __restrict__ ecol,
    const unsigned short* __restrict__ zs, const unsigned short* __restrict__ zt,
    const float* __restrict__ w1, const float* __restrict__ b1,
    const float* __restrict__ w2, const float* __restrict__ b2,
    float* __restrict__ out)
{
    const int lane = threadIdx.x & 63, wid = threadIdx.x >> 6;
    const int l16 = lane & 15, q = lane >> 4;
    s16x8 bfr[4][4];  // d1_w [128][64] as B-fragments
#pragma unroll
    for (int ks = 0; ks < 4; ks++)
#pragma unroll
        for (int nt = 0; nt < 4; nt++)
#pragma unroll
            for (int i = 0; i < 8; i++)
                bfr[ks][nt][i] = (short)f2bf(w1[(ks * 32 + q * 8 + i) * OUTD + nt * 16 + l16]);
    float b1v[4], w2v[4];
#pragma unroll
    for (int nt = 0; nt < 4; nt++) {
        b1v[nt] = b1[nt * 16 + l16];
        w2v[nt] = w2[nt * 16 + l16];
    }
    const float b2v = b2[0];
    const int n_tiles = E_LBL >> 4;
    for (int tile = blockIdx.x * 4 + wid; tile < n_tiles; tile += gridDim.x * 4) {
        const int em = tile * 16 + l16;
        const size_t r = (size_t)erow[em], c = (size_t)ecol[em];
        f32x4 acc[4] = {};
        s16x8 a0 = *(const s16x8*)(zs + r * OUTD + q * 8);
        s16x8 a1 = *(const s16x8*)(zs + r * OUTD + 32 + q * 8);
        s16x8 a2 = *(const s16x8*)(zt + c * OUTD + q * 8);
        s16x8 a3 = *(const s16x8*)(zt + c * OUTD + 32 + q * 8);
#pragma unroll
        for (int nt = 0; nt < 4; nt++) {
            acc[nt] = __builtin_amdgcn_mfma_f32_16x16x32_bf16(a0, bfr[0][nt], acc[nt], 0, 0, 0);
            acc[nt] = __builtin_amdgcn_mfma_f32_16x16x32_bf16(a1, bfr[1][nt], acc[nt], 0, 0, 0);
            acc[nt] = __builtin_amdgcn_mfma_f32_16x16x32_bf16(a2, bfr[2][nt], acc[nt], 0, 0, 0);
            acc[nt] = __builtin_amdgcn_mfma_f32_16x16x32_bf16(a3, bfr[3][nt], acc[nt], 0, 0, 0);
        }
        float s[4] = {0.0f, 0.0f, 0.0f, 0.0f};
#pragma unroll
        for (int nt = 0; nt < 4; nt++)
#pragma unroll
            for (int i = 0; i < 4; i++)
                s[i] += fmaxf(acc[nt][i] + b1v[nt], 0.0f) * w2v[nt];
#pragma unroll
        for (int off = 8; off >= 1; off >>= 1)
#pragma unroll
            for (int i = 0; i < 4; i++)
                s[i] += __shfl_down(s[i], off, 16);
        if (l16 == 0) {
#pragma unroll
            for (int i = 0; i < 4; i++)
                out[tile * 16 + q * 4 + i] = s[i] + b2v;
        }
    }
}

// =================== host side ===================
static void build_csr(const int* src, const int* dst, int n_edges, int n_dst,
                      int* rp, int* sl, int* bsums, hipStream_t stream) {
    hipMemsetAsync(rp, 0, (size_t)n_dst * 4, stream);
    hist_kernel<<<(n_edges + 255) / 256, 256, 0, stream>>>(dst, n_edges, rp);
    const int nb = (n_dst + SCAN_TILE - 1) / SCAN_TILE;
    scan1_kernel<<<nb, 256, 0, stream>>>(rp, n_dst, bsums);
    scan2_kernel<<<1, 256, 0, stream>>>(bsums, nb);
    scan3_kernel<<<nb, 256, 0, stream>>>(rp, n_dst, bsums);
    fill_kernel<<<(n_edges + 255) / 256, 256, 0, stream>>>(src, dst, n_edges, rp, sl);
}

extern "C" void kernel_launch(void* const* d_in, const int* in_sizes, int n_in,
                              void* d_out, int out_size, void* d_ws, size_t ws_size,
                              hipStream_t stream) {
    (void)in_sizes; (void)n_in; (void)out_size; (void)ws_size;
    const int* sotu_ids  = (const int*)d_in[0];
    const int* taxon_ids = (const int*)d_in[1];
    const int* ett_src   = (const int*)d_in[2];
    const int* ett_dst   = (const int*)d_in[3];
    const int* ets_src   = (const int*)d_in[4];
    const int* ets_dst   = (const int*)d_in[5];
    const int* elbl_row  = (const int*)d_in[6];
    const int* elbl_col  = (const int*)d_in[7];
    const float* sotu_emb  = (const float*)d_in[8];
    const float* taxon_emb = (const float*)d_in[9];
    const float* s1_wl = (const float*)d_in[10]; const float* s1_bl = (const float*)d_in[11]; const float* s1_wr = (const float*)d_in[12];
    const float* s2_wl = (const float*)d_in[13]; const float* s2_bl = (const float*)d_in[14]; const float* s2_wr = (const float*)d_in[15];
    const float* s3_wl = (const float*)d_in[16]; const float* s3_bl = (const float*)d_in[17]; const float* s3_wr = (const float*)d_in[18];
    const float* sl_w  = (const float*)d_in[19]; const float* sl_b  = (const float*)d_in[20];
    const float* t1_wl = (const float*)d_in[21]; const float* t1_bl = (const float*)d_in[22]; const float* t1_wr = (const float*)d_in[23];
    const float* t2_wl = (const float*)d_in[24]; const float* t2_bl = (const float*)d_in[25]; const float* t2_wr = (const float*)d_in[26];
    const float* tl_w  = (const float*)d_in[27]; const float* tl_b  = (const float*)d_in[28];
    const float* d1_w  = (const float*)d_in[29]; const float* d1_b  = (const float*)d_in[30];
    const float* d2_w  = (const float*)d_in[31]; const float* d2_b  = (const float*)d_in[32];
    float* out = (float*)d_out;

    // workspace (~365 MB with alias)
    char* ws = (char*)d_ws;
    size_t off = 0;
    auto alloc = [&](size_t bytes) { void* p = ws + off; off = (off + bytes + 255) & ~(size_t)255; return p; };
    unsigned short* tb      = (unsigned short*)alloc((size_t)N_TAXON * HID * 2);  // 51.2 MB bf16 taxon emb
    unsigned short* taxon_x = (unsigned short*)alloc((size_t)N_TAXON * HID * 2);  // 51.2 MB
    unsigned short* tx1     = (unsigned short*)alloc((size_t)N_TAXON * HID * 2);  // 51.2 MB
    unsigned short* tx2     = (unsigned short*)alloc((size_t)N_TAXON * HID * 2);  // 51.2 MB
    unsigned short* sotu_x  = (unsigned short*)alloc((size_t)N_SOTU * HID * 2);   // 128 MB
    unsigned short* z_taxon = (unsigned short*)alloc((size_t)N_TAXON * OUTD * 2); // 25.6 MB
    int* rp_ts = (int*)alloc((size_t)N_SOTU * 4);    // 2 MB
    int* sl_ts = (int*)alloc((size_t)E_TS * 4);      // 4 MB
    int* rp_tt = (int*)alloc((size_t)N_TAXON * 4);   // 0.8 MB
    int* sl_tt = (int*)alloc((size_t)E_TT * 4);      // 0.8 MB
    int* bsums = (int*)alloc(256 * 4);
    // z_sotu (64 MB) aliases tx1..tx2 (102.4 MB); both dead before sl-proj writes it
    unsigned short* z_sotu = tx1;

    // CSR builds (tt used by s1/t1/t2; ts by s2/s3)
    build_csr(ett_src, ett_dst, E_TT, N_TAXON, rp_tt, sl_tt, bsums, stream);
    build_csr(ets_src, ets_dst, E_TS, N_SOTU, rp_ts, sl_ts, bsums, stream);

    // taxon embedding -> bf16 (id indirection baked in)
    cvt_kernel<<<(N_TAXON * 16 + 255) / 256, 256, 0, stream>>>(N_TAXON, taxon_emb, taxon_ids, tb);

    // s1 / t1: fused A1-gather + SAGE over tt (each re-gathers; E_TT is small)
    fsage_kernel<<<512, 256, 0, stream>>>(N_TAXON, 0, tb, rp_tt, sl_tt, N_TAXON, E_TT,
                                          nullptr, tb, nullptr, s1_wl, s1_wr, s1_bl, taxon_x);
    fsage_kernel<<<512, 256, 0, stream>>>(N_TAXON, 0, tb, rp_tt, sl_tt, N_TAXON, E_TT,
                                          nullptr, tb, nullptr, t1_wl, t1_wr, t1_bl, tx1);

    // taxon tail: t2 (gather reads tx1 live -> must write tx2), then tl head
    fsage_kernel<<<512, 256, 0, stream>>>(N_TAXON, 0, tx1, rp_tt, sl_tt, N_TAXON, E_TT,
                                          nullptr, tx1, nullptr, t2_wl, t2_wr, t2_bl, tx2);
    proj_kernel<<<1024, 256, 0, stream>>>(N_TAXON, tx2, tl_w, tl_b, z_taxon);

    // s2: fused A2-gather (tb) + SAGE, full 500K rows in one launch
    fsage_kernel<<<512, 256, 0, stream>>>(N_SOTU, 0, tb, rp_ts, sl_ts, N_SOTU, E_TS,
                                          sotu_emb, nullptr, sotu_ids, s2_wl, s2_wr, s2_bl, sotu_x);
    // s3: fused A3-gather (taxon_x) + SAGE, in-place on sotu_x (x rows are wave-local)
    fsage_kernel<<<512, 256, 0, stream>>>(N_SOTU, 0, taxon_x, rp_ts, sl_ts, N_SOTU, E_TS,
                                          nullptr, sotu_x, nullptr, s3_wl, s3_wr, s3_bl, sotu_x);
    // sl head (tx1/tx2 dead -> z_sotu lives there)
    proj_kernel<<<1024, 256, 0, stream>>>(N_SOTU, sotu_x, sl_w, sl_b, z_sotu);

    // edge decoder
    dec_kernel<<<1024, 256, 0, stream>>>(elbl_row, elbl_col, z_sotu, z_taxon,
                                         d1_w, d1_b, d2_w, d2_b, out);
}

// Round 3
// 1340.804 us; speedup vs baseline: 1.2152x; 1.1152x over previous
//
#include <hip/hip_runtime.h>

#define HID 128
#define OUTD 64
#define N_SOTU 500000
#define N_TAXON 200000
#define E_TT 200000
#define E_TS 1000000
#define E_LBL 500000
#define SCAN_TILE 2048   // elements per scan block (256 thr x 8)

typedef short s16x8 __attribute__((ext_vector_type(8)));   // 8 bf16 (4 VGPRs) MFMA frag
typedef float f32x4 __attribute__((ext_vector_type(4)));

__device__ __forceinline__ unsigned short f2bf(float f) {  // f32 -> bf16 bits, RNE
    unsigned u = __builtin_bit_cast(unsigned, f);
    u += 0x7FFFu + ((u >> 16) & 1u);
    return (unsigned short)(u >> 16);
}
__device__ __forceinline__ float bf2f(unsigned short h) {
    unsigned u = ((unsigned)h) << 16;
    return __builtin_bit_cast(float, u);
}

// =================== CSR build: hist -> scan (3 kernels) -> fill ===================
__global__ void hist_kernel(const int* __restrict__ dst, int n, int* __restrict__ rp) {
    int e = blockIdx.x * 256 + threadIdx.x;
    if (e < n) atomicAdd(&rp[dst[e]], 1);
}

__global__ __launch_bounds__(256) void scan1_kernel(int* __restrict__ a, int n, int* __restrict__ bsums) {
    __shared__ int tsum[256];
    const int t = threadIdx.x;
    const int base = blockIdx.x * SCAN_TILE + t * 8;
    int v[8]; int s = 0;
#pragma unroll
    for (int i = 0; i < 8; i++) {
        int x = (base + i < n) ? a[base + i] : 0;
        s += x; v[i] = s;
    }
    tsum[t] = s;
    __syncthreads();
    for (int off = 1; off < 256; off <<= 1) {
        int x = (t >= off) ? tsum[t - off] : 0;
        __syncthreads();
        tsum[t] += x;
        __syncthreads();
    }
    const int prev = (t > 0) ? tsum[t - 1] : 0;
#pragma unroll
    for (int i = 0; i < 8; i++)
        if (base + i < n) a[base + i] = v[i] + prev;
    if (t == 255) bsums[blockIdx.x] = tsum[255];
}

__global__ __launch_bounds__(256) void scan2_kernel(int* __restrict__ bsums, int nb) {
    __shared__ int tsum[256];
    const int t = threadIdx.x;
    tsum[t] = (t < nb) ? bsums[t] : 0;
    __syncthreads();
    for (int off = 1; off < 256; off <<= 1) {
        int x = (t >= off) ? tsum[t - off] : 0;
        __syncthreads();
        tsum[t] += x;
        __syncthreads();
    }
    if (t < nb) bsums[t] = tsum[t];
}

__global__ __launch_bounds__(256) void scan3_kernel(int* __restrict__ a, int n, const int* __restrict__ bsums) {
    const int b = blockIdx.x;
    if (b == 0) return;
    const int add = bsums[b - 1];
    const int base = b * SCAN_TILE + threadIdx.x * 8;
#pragma unroll
    for (int i = 0; i < 8; i++)
        if (base + i < n) a[base + i] += add;
}

__global__ void fill_kernel(const int* __restrict__ src, const int* __restrict__ dst, int n,
                            int* __restrict__ rp, int* __restrict__ sl) {
    int e = blockIdx.x * 256 + threadIdx.x;
    if (e < n) {
        int pos = atomicSub(&rp[dst[e]], 1) - 1;
        sl[pos] = src[e];
    }
}

// =================== embedding f32 -> bf16 (with id indirection baked in) ===================
__global__ __launch_bounds__(256) void cvt_kernel(
    int n_rows, const float* __restrict__ xf, const int* __restrict__ ids,
    unsigned short* __restrict__ o)
{
    int idx = blockIdx.x * 256 + threadIdx.x;     // one thread = 8 feats
    if (idx >= n_rows * 16) return;
    int r = idx >> 4, l = idx & 15;
    int s = ids ? ids[r] : r;
    const float* p = xf + (size_t)s * HID + l * 8;
    float4 v0 = *(const float4*)p;
    float4 v1 = *(const float4*)(p + 4);
    s16x8 ov;
    ov[0] = (short)f2bf(v0.x); ov[1] = (short)f2bf(v0.y);
    ov[2] = (short)f2bf(v0.z); ov[3] = (short)f2bf(v0.w);
    ov[4] = (short)f2bf(v1.x); ov[5] = (short)f2bf(v1.y);
    ov[6] = (short)f2bf(v1.z); ov[7] = (short)f2bf(v1.w);
    *(s16x8*)(o + (size_t)r * HID + l * 8) = ov;
}

// =================== fused gather + SAGE ===================
// out = relu( mean_{nb}(gsrc) @ wl + x @ wr + bl ).
// Gather phase is a branchless 3-deep chain (rp -> sl -> rows) with the whole 16-row
// tile's loads in flight at once (MLP), then MFMA 16x16x32 bf16 with K=256 = [agg | x].
__device__ __forceinline__ int wt_idx(int n, int k) {
    return n * 256 + ((((k >> 3) ^ n) & 31) << 3) + (k & 7);
}

__global__ __launch_bounds__(256, 2) void fsage_kernel(
    int n_rows, int row0,
    const unsigned short* __restrict__ gsrc,   // gather source rows, bf16 [*, HID]
    const int* __restrict__ rp, const int* __restrict__ sl,
    int n_dst_total, int n_edges,
    const float* __restrict__ xf, const unsigned short* __restrict__ xb,  // one non-null
    const int* __restrict__ xids,    // if null, xrow = row0 + local
    const float* __restrict__ wl, const float* __restrict__ wr,
    const float* __restrict__ bl,
    unsigned short* __restrict__ out)  // pre-offset by row0*HID
{
    __shared__ __align__(16) unsigned short WT[128 * 256];       // 64 KB weights
    __shared__ __align__(16) unsigned short AGG[4][16 * 128];    // 16 KB per-wave staging
    for (int idx = threadIdx.x; idx < 128 * 128; idx += 256) {
        int n = idx & 127, k = idx >> 7;
        WT[wt_idx(n, k)]       = f2bf(wl[idx]);   // wl[k][n]
        WT[wt_idx(n, k + 128)] = f2bf(wr[idx]);   // wr[k][n]
    }
    __syncthreads();
    const int lane = threadIdx.x & 63, wid = threadIdx.x >> 6;
    const int l16 = lane & 15, q = lane >> 4;
    const int n_tiles = n_rows >> 4;
    const int stride = gridDim.x * 4;
    for (int tile = blockIdx.x * 4 + wid; tile < n_tiles; tile += stride) {
        const int base = tile << 4;
        const int lrow = base + l16;
        const size_t xrow = xids ? (size_t)xids[lrow] : (size_t)(row0 + lrow);
        // ---- x-row load issued first; flies with the gather loads ----
        float4 xv[8];
        s16x8 axb[4];
        if (xf) {
            const float* xp = xf + xrow * HID + q * 8;
#pragma unroll
            for (int ks = 0; ks < 4; ++ks) {
                xv[ks * 2]     = *(const float4*)(xp + ks * 32);
                xv[ks * 2 + 1] = *(const float4*)(xp + ks * 32 + 4);
            }
        } else {
            const unsigned short* xp = xb + xrow * HID + q * 8;
#pragma unroll
            for (int ks = 0; ks < 4; ++ks) axb[ks] = *(const s16x8*)(xp + ks * 32);
        }
        // ---- gather: branchless wide phase, all 16 rows' loads concurrent ----
        int st[4], cc[4];
        s16x8 r[4][4];
        float wgt[4][4];
#pragma unroll
        for (int it = 0; it < 4; ++it) {
            const int lr = it * 4 + q;
            const int d = row0 + base + lr;
            const int s_ = rp[d];
            const int e_ = (d + 1 < n_dst_total) ? rp[d + 1] : n_edges;
            st[it] = s_;
            const int c = e_ - s_;
            cc[it] = c;
            const int js = (s_ < n_edges) ? s_ : (n_edges - 1);   // clamp (empty last buckets)
            const int i1 = (c > 1) ? s_ + 1 : js;
            const int i2 = (c > 2) ? s_ + 2 : js;
            const int i3 = (c > 3) ? s_ + 3 : js;
            const int s0 = sl[js], s1 = sl[i1], s2 = sl[i2], s3 = sl[i3];
            r[it][0] = *(const s16x8*)(gsrc + (size_t)s0 * HID + l16 * 8);
            r[it][1] = *(const s16x8*)(gsrc + (size_t)s1 * HID + l16 * 8);
            r[it][2] = *(const s16x8*)(gsrc + (size_t)s2 * HID + l16 * 8);
            r[it][3] = *(const s16x8*)(gsrc + (size_t)s3 * HID + l16 * 8);
            wgt[it][0] = (c > 0) ? 1.0f : 0.0f;
            wgt[it][1] = (c > 1) ? 1.0f : 0.0f;
            wgt[it][2] = (c > 2) ? 1.0f : 0.0f;
            wgt[it][3] = (c > 3) ? 1.0f : 0.0f;
        }
        // ---- accumulate + rare serial tail (deg > 4), then stage to LDS ----
#pragma unroll
        for (int it = 0; it < 4; ++it) {
            float acc[8];
#pragma unroll
            for (int i = 0; i < 8; i++)
                acc[i] = wgt[it][0] * bf2f((unsigned short)r[it][0][i])
                       + wgt[it][1] * bf2f((unsigned short)r[it][1][i])
                       + wgt[it][2] * bf2f((unsigned short)r[it][2][i])
                       + wgt[it][3] * bf2f((unsigned short)r[it][3][i]);
            if (cc[it] > 4) {
                const int e_ = st[it] + cc[it];
                for (int j = st[it] + 4; j < e_; ++j) {
                    const int s = sl[j];
                    s16x8 b = *(const s16x8*)(gsrc + (size_t)s * HID + l16 * 8);
#pragma unroll
                    for (int i = 0; i < 8; i++) acc[i] += bf2f((unsigned short)b[i]);
                }
            }
            const float inv = (cc[it] > 0) ? 1.0f / (float)cc[it] : 0.0f;
            const int lr = it * 4 + q;
            s16x8 o;
#pragma unroll
            for (int i = 0; i < 8; i++) o[i] = (short)f2bf(acc[i] * inv);
            // XOR-swizzled store (16B granule)
            *(s16x8*)&AGG[wid][lr * 128 + ((l16 * 8) ^ ((lr & 7) << 3))] = o;
        }
        asm volatile("s_waitcnt lgkmcnt(0)" ::: "memory");   // wave-local staging visible
        // ---- x fragments (convert f32 path now, loads long since landed) ----
        s16x8 ax[4];
        if (xf) {
#pragma unroll
            for (int ks = 0; ks < 4; ++ks) {
                float4 v0 = xv[ks * 2], v1 = xv[ks * 2 + 1];
                ax[ks][0] = (short)f2bf(v0.x); ax[ks][1] = (short)f2bf(v0.y);
                ax[ks][2] = (short)f2bf(v0.z); ax[ks][3] = (short)f2bf(v0.w);
                ax[ks][4] = (short)f2bf(v1.x); ax[ks][5] = (short)f2bf(v1.y);
                ax[ks][6] = (short)f2bf(v1.z); ax[ks][7] = (short)f2bf(v1.w);
            }
        } else {
#pragma unroll
            for (int ks = 0; ks < 4; ++ks) ax[ks] = axb[ks];
        }
        // ---- MFMA phase ----
        f32x4 acc4[8] = {};
        // K = 0..127 : aggregation from swizzled LDS
#pragma unroll
        for (int ks = 0; ks < 4; ks++) {
            const int cu = ks * 32 + q * 8;
            s16x8 a = *(const s16x8*)&AGG[wid][l16 * 128 + (cu ^ ((l16 & 7) << 3))];
#pragma unroll
            for (int nt = 0; nt < 8; nt++) {
                s16x8 b = *(const s16x8*)&WT[wt_idx(nt * 16 + l16, cu)];
                acc4[nt] = __builtin_amdgcn_mfma_f32_16x16x32_bf16(a, b, acc4[nt], 0, 0, 0);
            }
        }
        // K = 128..255 : x_dst from regs
#pragma unroll
        for (int ks = 0; ks < 4; ks++) {
            const int kb = 128 + ks * 32 + q * 8;
#pragma unroll
            for (int nt = 0; nt < 8; nt++) {
                s16x8 b = *(const s16x8*)&WT[wt_idx(nt * 16 + l16, kb)];
                acc4[nt] = __builtin_amdgcn_mfma_f32_16x16x32_bf16(ax[ks], b, acc4[nt], 0, 0, 0);
            }
        }
        // epilogue. D layout (m89-verified): col = lane&15, row = (lane>>4)*4 + i
#pragma unroll
        for (int nt = 0; nt < 8; nt++) {
            const int n = nt * 16 + l16;
            const float bv = bl[n];
#pragma unroll
            for (int i = 0; i < 4; i++) {
                float v = acc4[nt][i] + bv;
                out[(size_t)(base + q * 4 + i) * HID + n] = f2bf(fmaxf(v, 0.0f));
            }
        }
    }
}

// =================== linear head: z = x @ w + b  ([N,128]@[128,64]) ===================
__global__ __launch_bounds__(256) void proj_kernel(
    int n_nodes, const unsigned short* __restrict__ x,
    const float* __restrict__ w, const float* __restrict__ bias, unsigned short* __restrict__ z)
{
    const int lane = threadIdx.x & 63, wid = threadIdx.x >> 6;
    const int l16 = lane & 15, q = lane >> 4;
    s16x8 bfr[4][4];
#pragma unroll
    for (int ks = 0; ks < 4; ks++)
#pragma unroll
        for (int nt = 0; nt < 4; nt++)
#pragma unroll
            for (int i = 0; i < 8; i++)
                bfr[ks][nt][i] = (short)f2bf(w[(ks * 32 + q * 8 + i) * OUTD + nt * 16 + l16]);
    const int n_tiles = n_nodes >> 4;
    const int stride = gridDim.x * 4;
    for (int tile = blockIdx.x * 4 + wid; tile < n_tiles; tile += stride) {
        const int base = tile << 4;
        const size_t mrow = (size_t)(base + l16);
        f32x4 acc[4] = {};
#pragma unroll
        for (int ks = 0; ks < 4; ks++) {
            s16x8 a = *(const s16x8*)(x + mrow * HID + ks * 32 + q * 8);
#pragma unroll
            for (int nt = 0; nt < 4; nt++)
                acc[nt] = __builtin_amdgcn_mfma_f32_16x16x32_bf16(a, bfr[ks][nt], acc[nt], 0, 0, 0);
        }
#pragma unroll
        for (int nt = 0; nt < 4; nt++) {
            const int n = nt * 16 + l16;
            const float bv = bias[n];
#pragma unroll
            for (int i = 0; i < 4; i++)
                z[(size_t)(base + q * 4 + i) * OUTD + n] = f2bf(acc[nt][i] + bv);
        }
    }
}

// =================== edge decoder ===================
__global__ __launch_bounds__(256) void dec_kernel(
    const int* __restrict__ erow, const int* __restrict__ ecol,
    const unsigned short* __restrict__ zs, const unsigned short* __restrict__ zt,
    const float* __restrict__ w1, const float* __restrict__ b1,
    const float* __restrict__ w2, const float* __restrict__ b2,
    float* __restrict__ out)
{
    const int lane = threadIdx.x & 63, wid = threadIdx.x >> 6;
    const int l16 = lane & 15, q = lane >> 4;
    s16x8 bfr[4][4];  // d1_w [128][64] as B-fragments
#pragma unroll
    for (int ks = 0; ks < 4; ks++)
#pragma unroll
        for (int nt = 0; nt < 4; nt++)
#pragma unroll
            for (int i = 0; i < 8; i++)
                bfr[ks][nt][i] = (short)f2bf(w1[(ks * 32 + q * 8 + i) * OUTD + nt * 16 + l16]);
    float b1v[4], w2v[4];
#pragma unroll
    for (int nt = 0; nt < 4; nt++) {
        b1v[nt] = b1[nt * 16 + l16];
        w2v[nt] = w2[nt * 16 + l16];
    }
    const float b2v = b2[0];
    const int n_tiles = E_LBL >> 4;
    for (int tile = blockIdx.x * 4 + wid; tile < n_tiles; tile += gridDim.x * 4) {
        const int em = tile * 16 + l16;
        const size_t r = (size_t)erow[em], c = (size_t)ecol[em];
        f32x4 acc[4] = {};
        s16x8 a0 = *(const s16x8*)(zs + r * OUTD + q * 8);
        s16x8 a1 = *(const s16x8*)(zs + r * OUTD + 32 + q * 8);
        s16x8 a2 = *(const s16x8*)(zt + c * OUTD + q * 8);
        s16x8 a3 = *(const s16x8*)(zt + c * OUTD + 32 + q * 8);
#pragma unroll
        for (int nt = 0; nt < 4; nt++) {
            acc[nt] = __builtin_amdgcn_mfma_f32_16x16x32_bf16(a0, bfr[0][nt], acc[nt], 0, 0, 0);
            acc[nt] = __builtin_amdgcn_mfma_f32_16x16x32_bf16(a1, bfr[1][nt], acc[nt], 0, 0, 0);
            acc[nt] = __builtin_amdgcn_mfma_f32_16x16x32_bf16(a2, bfr[2][nt], acc[nt], 0, 0, 0);
            acc[nt] = __builtin_amdgcn_mfma_f32_16x16x32_bf16(a3, bfr[3][nt], acc[nt], 0, 0, 0);
        }
        float s[4] = {0.0f, 0.0f, 0.0f, 0.0f};
#pragma unroll
        for (int nt = 0; nt < 4; nt++)
#pragma unroll
            for (int i = 0; i < 4; i++)
                s[i] += fmaxf(acc[nt][i] + b1v[nt], 0.0f) * w2v[nt];
#pragma unroll
        for (int off = 8; off >= 1; off >>= 1)
#pragma unroll
            for (int i = 0; i < 4; i++)
                s[i] += __shfl_down(s[i], off, 16);
        if (l16 == 0) {
#pragma unroll
            for (int i = 0; i < 4; i++)
                out[tile * 16 + q * 4 + i] = s[i] + b2v;
        }
    }
}

// =================== host side ===================
static void build_csr(const int* src, const int* dst, int n_edges, int n_dst,
                      int* rp, int* sl, int* bsums, hipStream_t stream) {
    hipMemsetAsync(rp, 0, (size_t)n_dst * 4, stream);
    hist_kernel<<<(n_edges + 255) / 256, 256, 0, stream>>>(dst, n_edges, rp);
    const int nb = (n_dst + SCAN_TILE - 1) / SCAN_TILE;
    scan1_kernel<<<nb, 256, 0, stream>>>(rp, n_dst, bsums);
    scan2_kernel<<<1, 256, 0, stream>>>(bsums, nb);
    scan3_kernel<<<nb, 256, 0, stream>>>(rp, n_dst, bsums);
    fill_kernel<<<(n_edges + 255) / 256, 256, 0, stream>>>(src, dst, n_edges, rp, sl);
}

extern "C" void kernel_launch(void* const* d_in, const int* in_sizes, int n_in,
                              void* d_out, int out_size, void* d_ws, size_t ws_size,
                              hipStream_t stream) {
    (void)in_sizes; (void)n_in; (void)out_size; (void)ws_size;
    const int* sotu_ids  = (const int*)d_in[0];
    const int* taxon_ids = (const int*)d_in[1];
    const int* ett_src   = (const int*)d_in[2];
    const int* ett_dst   = (const int*)d_in[3];
    const int* ets_src   = (const int*)d_in[4];
    const int* ets_dst   = (const int*)d_in[5];
    const int* elbl_row  = (const int*)d_in[6];
    const int* elbl_col  = (const int*)d_in[7];
    const float* sotu_emb  = (const float*)d_in[8];
    const float* taxon_emb = (const float*)d_in[9];
    const float* s1_wl = (const float*)d_in[10]; const float* s1_bl = (const float*)d_in[11]; const float* s1_wr = (const float*)d_in[12];
    const float* s2_wl = (const float*)d_in[13]; const float* s2_bl = (const float*)d_in[14]; const float* s2_wr = (const float*)d_in[15];
    const float* s3_wl = (const float*)d_in[16]; const float* s3_bl = (const float*)d_in[17]; const float* s3_wr = (const float*)d_in[18];
    const float* sl_w  = (const float*)d_in[19]; const float* sl_b  = (const float*)d_in[20];
    const float* t1_wl = (const float*)d_in[21]; const float* t1_bl = (const float*)d_in[22]; const float* t1_wr = (const float*)d_in[23];
    const float* t2_wl = (const float*)d_in[24]; const float* t2_bl = (const float*)d_in[25]; const float* t2_wr = (const float*)d_in[26];
    const float* tl_w  = (const float*)d_in[27]; const float* tl_b  = (const float*)d_in[28];
    const float* d1_w  = (const float*)d_in[29]; const float* d1_b  = (const float*)d_in[30];
    const float* d2_w  = (const float*)d_in[31]; const float* d2_b  = (const float*)d_in[32];
    float* out = (float*)d_out;

    // workspace (~365 MB with alias)
    char* ws = (char*)d_ws;
    size_t off = 0;
    auto alloc = [&](size_t bytes) { void* p = ws + off; off = (off + bytes + 255) & ~(size_t)255; return p; };
    unsigned short* tb      = (unsigned short*)alloc((size_t)N_TAXON * HID * 2);  // 51.2 MB bf16 taxon emb
    unsigned short* taxon_x = (unsigned short*)alloc((size_t)N_TAXON * HID * 2);  // 51.2 MB
    unsigned short* tx1     = (unsigned short*)alloc((size_t)N_TAXON * HID * 2);  // 51.2 MB
    unsigned short* tx2     = (unsigned short*)alloc((size_t)N_TAXON * HID * 2);  // 51.2 MB
    unsigned short* sotu_x  = (unsigned short*)alloc((size_t)N_SOTU * HID * 2);   // 128 MB
    unsigned short* z_taxon = (unsigned short*)alloc((size_t)N_TAXON * OUTD * 2); // 25.6 MB
    int* rp_ts = (int*)alloc((size_t)N_SOTU * 4);    // 2 MB
    int* sl_ts = (int*)alloc((size_t)E_TS * 4);      // 4 MB
    int* rp_tt = (int*)alloc((size_t)N_TAXON * 4);   // 0.8 MB
    int* sl_tt = (int*)alloc((size_t)E_TT * 4);      // 0.8 MB
    int* bsums = (int*)alloc(256 * 4);
    // z_sotu (64 MB) aliases tx1..tx2 (102.4 MB); both dead before sl-proj writes it
    unsigned short* z_sotu = tx1;

    // CSR builds (tt used by s1/t1/t2; ts by s2/s3)
    build_csr(ett_src, ett_dst, E_TT, N_TAXON, rp_tt, sl_tt, bsums, stream);
    build_csr(ets_src, ets_dst, E_TS, N_SOTU, rp_ts, sl_ts, bsums, stream);

    // taxon embedding -> bf16 (id indirection baked in)
    cvt_kernel<<<(N_TAXON * 16 + 255) / 256, 256, 0, stream>>>(N_TAXON, taxon_emb, taxon_ids, tb);

    // s1 / t1: fused A1-gather + SAGE over tt (each re-gathers; E_TT is small)
    fsage_kernel<<<512, 256, 0, stream>>>(N_TAXON, 0, tb, rp_tt, sl_tt, N_TAXON, E_TT,
                                          nullptr, tb, nullptr, s1_wl, s1_wr, s1_bl, taxon_x);
    fsage_kernel<<<512, 256, 0, stream>>>(N_TAXON, 0, tb, rp_tt, sl_tt, N_TAXON, E_TT,
                                          nullptr, tb, nullptr, t1_wl, t1_wr, t1_bl, tx1);

    // taxon tail: t2 (gather reads tx1 live -> must write tx2), then tl head
    fsage_kernel<<<512, 256, 0, stream>>>(N_TAXON, 0, tx1, rp_tt, sl_tt, N_TAXON, E_TT,
                                          nullptr, tx1, nullptr, t2_wl, t2_wr, t2_bl, tx2);
    proj_kernel<<<1024, 256, 0, stream>>>(N_TAXON, tx2, tl_w, tl_b, z_taxon);

    // s2: fused A2-gather (tb) + SAGE, full 500K rows in one launch
    fsage_kernel<<<512, 256, 0, stream>>>(N_SOTU, 0, tb, rp_ts, sl_ts, N_SOTU, E_TS,
                                          sotu_emb, nullptr, sotu_ids, s2_wl, s2_wr, s2_bl, sotu_x);
    // s3: fused A3-gather (taxon_x) + SAGE, in-place on sotu_x (x rows are wave-local)
    fsage_kernel<<<512, 256, 0, stream>>>(N_SOTU, 0, taxon_x, rp_ts, sl_ts, N_SOTU, E_TS,
                                          nullptr, sotu_x, nullptr, s3_wl, s3_wr, s3_bl, sotu_x);
    // sl head (tx1/tx2 dead -> z_sotu lives there)
    proj_kernel<<<1024, 256, 0, stream>>>(N_SOTU, sotu_x, sl_w, sl_b, z_sotu);

    // edge decoder
    dec_kernel<<<1024, 256, 0, stream>>>(elbl_row, elbl_col, z_sotu, z_taxon,
                                         d1_w, d1_b, d2_w, d2_b, out);
}